// Round 5
// baseline (467.008 us; speedup 1.0000x reference)
//
#include <hip/hip_runtime.h>
#include <math.h>

// ---------------------------------------------------------------------------
// CrossPath: dual cross-attention block, MI355X (gfx950).
//   B=4, N=2304, C=256, H=8, D=32, out = 2 x [B,C,96,96] float32
// Inputs float32 (runtime-sniffed). Internal: bf16 MFMA, fp32 accumulation.
// R12: attn pipeline restructure (latency-bound per R11 counters):
//   - double-buffered K/V LDS, ONE raw s_barrier per kc with lgkmcnt(0) only
//     (no vmcnt drain -> global prefetch stays in flight across barriers)
//   - prefetch depth 2 (chunk kc+2 issued at kc; ~800 cyc cover vs HBM ~900)
//   - split PV accumulators (o0/o1) halving the dependent MFMA chain
//   - 2 waves/block (64 q), grid 2304 blocks = 9/CU exact balance
// ---------------------------------------------------------------------------

typedef __attribute__((ext_vector_type(8))) short short8;   // 8 bf16 = 4 VGPRs
typedef __attribute__((ext_vector_type(4))) float f32x4;
typedef __attribute__((ext_vector_type(16))) float f32x16;
typedef __attribute__((ext_vector_type(2))) unsigned uint32x2;

#define MFMA16(a, b, c) __builtin_amdgcn_mfma_f32_16x16x32_bf16((a), (b), (c), 0, 0, 0)
#define MFMA32(a, b, c) __builtin_amdgcn_mfma_f32_32x32x16_bf16((a), (b), (c), 0, 0, 0)

__device__ __forceinline__ float bf2f(ushort u) {
    union { unsigned u; float f; } x; x.u = ((unsigned)u) << 16; return x.f;
}
__device__ __forceinline__ ushort f2bf(float f) {
    union { float f; unsigned u; } x; x.f = f;
    unsigned u = x.u;
    return (ushort)((u + 0x7fffu + ((u >> 16) & 1u)) >> 16);   // RNE
}
// HW packed RNE conversion: D = {bf16(b)<<16 | bf16(a)}
__device__ __forceinline__ unsigned cvt_pk_bf16(float a, float b) {
    unsigned r;
    asm("v_cvt_pk_bf16_f32 %0, %1, %2" : "=v"(r) : "v"(a), "v"(b));
    return r;
}
// Exchange upper 32 lanes of a with lower 32 lanes of b (gfx950 builtin).
__device__ __forceinline__ void plswap(unsigned &a, unsigned &b) {
    uint32x2 r = __builtin_amdgcn_permlane32_swap(a, b, false, false);
    a = r[0]; b = r[1];
}
// Workgroup barrier WITHOUT vmcnt drain: LDS ops complete, global loads
// (feeding only this wave's registers) stay in flight.
__device__ __forceinline__ void wavebar() {
    asm volatile("s_waitcnt lgkmcnt(0)" ::: "memory");
    __builtin_amdgcn_s_barrier();
}

// ---------------------------------------------------------------------------
// Dtype sniffer: flag=1 means f32 inputs.
// ---------------------------------------------------------------------------
__global__ void sniff_kernel(const ushort* __restrict__ x, int* __restrict__ flag)
{
    int lane = threadIdx.x;
    ushort u = x[lane * 2];
    int e = (u >> 7) & 0xFF;
    int outlier = (e < 100 || e > 135) ? 1 : 0;
    unsigned long long m = __ballot(outlier);
    if (lane == 0) *flag = (__popcll(m) >= 16) ? 1 : 0;
}

// ---------------------------------------------------------------------------
// Canonicalize all 12 weight/param arrays to bf16 at fixed offsets in ws.
// ---------------------------------------------------------------------------
__global__ __launch_bounds__(256) void convert_params(
    const void* s0, const void* s1, const void* s2, const void* s3,
    const void* s4, const void* s5, const void* s6, const void* s7,
    const void* s8, const void* s9, const void* s10, const void* s11,
    ushort* __restrict__ dst, const int* __restrict__ flag)
{
    int idx = blockIdx.x * 256 + threadIdx.x;
    if (idx >= 525824) return;
    const void* src; int off;
    if      (idx < 65536)  { src = s0;  off = idx; }
    else if (idx < 196608) { src = s1;  off = idx - 65536; }
    else if (idx < 262144) { src = s2;  off = idx - 196608; }
    else if (idx < 393216) { src = s3;  off = idx - 262144; }
    else if (idx < 458752) { src = s4;  off = idx - 393216; }
    else if (idx < 524288) { src = s5;  off = idx - 458752; }
    else if (idx < 524544) { src = s6;  off = idx - 524288; }
    else if (idx < 524800) { src = s7;  off = idx - 524544; }
    else if (idx < 525056) { src = s8;  off = idx - 524800; }
    else if (idx < 525312) { src = s9;  off = idx - 525056; }
    else if (idx < 525568) { src = s10; off = idx - 525312; }
    else                   { src = s11; off = idx - 525568; }
    ushort v = (*flag) ? f2bf(((const float*)src)[off])
                       : ((const ushort*)src)[off];
    dst[idx] = v;
}

// ---------------------------------------------------------------------------
// Pre-convert x1/x2 -> bf16 once (8 elems/thread).
// ---------------------------------------------------------------------------
__global__ __launch_bounds__(256) void convert_x(
    const void* __restrict__ x1, const void* __restrict__ x2,
    ushort* __restrict__ o1, ushort* __restrict__ o2,
    const int* __restrict__ flag)
{
    int idx = blockIdx.x * 256 + threadIdx.x;      // 2304 blocks -> 589824 thr
    int which = idx >= 294912;
    int off = (which ? idx - 294912 : idx) * 8;
    const void* src = which ? x2 : x1;
    ushort* dst = which ? o2 : o1;
    if (*flag) {
        const float* p = (const float*)src + off;
        float4 a = *(const float4*)p;
        float4 c = *(const float4*)(p + 4);
        uint4 u;
        u.x = cvt_pk_bf16(a.x, a.y);
        u.y = cvt_pk_bf16(a.z, a.w);
        u.z = cvt_pk_bf16(c.x, c.y);
        u.w = cvt_pk_bf16(c.z, c.w);
        *(uint4*)(dst + off) = u;
    } else {
        *(uint4*)(dst + off) = *(const uint4*)((const ushort*)src + off);
    }
}

// ---------------------------------------------------------------------------
// GEMM: C[M,N] = A[M,K]*W[N,K]^T, bf16 MFMA 16x16x32, tile 64x64, 4 waves.
// Two stacked problems (rows [0,mhalf) use W/bias/Kh/Vt, rows [mhalf,M) use
// W2/bias2/Kh2/Vt2). mode 0: plain C (+bias/relu). mode 1 (merged QKV,
// N=768): col<256 -> Q row-major SCALED by scale*log2e; col<512 ->
// Kh[b][h][tok][32]; else -> Vt[b][h][d][2304].
// ---------------------------------------------------------------------------
__global__ __launch_bounds__(256) void gemm_bt(
    const void* __restrict__ Ain, const ushort* __restrict__ W,
    ushort* __restrict__ C, const ushort* __restrict__ bias,
    int M, int N, int K, int relu, const int* __restrict__ dflag, int a_ext,
    int mode, ushort* __restrict__ Kh, ushort* __restrict__ Vt,
    const ushort* __restrict__ W2, const ushort* __restrict__ bias2,
    ushort* __restrict__ Kh2, ushort* __restrict__ Vt2, int mhalf)
{
    __shared__ __align__(16) ushort As[64][40];
    __shared__ __align__(16) ushort Ws[64][40];

    const int m0 = blockIdx.x * 64;
    const int n0 = blockIdx.y * 64;
    const int tid = threadIdx.x;
    const int w = tid >> 6;
    const int lane = tid & 63;
    const int lm = lane & 15;
    const int quad = lane >> 4;
    const int a32 = a_ext ? *dflag : 0;

    const int side = (mhalf && m0 >= mhalf) ? 1 : 0;
    const ushort* Wu = side ? W2 : W;
    const ushort* bu = side ? bias2 : bias;
    ushort* Khu = side ? Kh2 : Kh;
    ushort* Vtu = side ? Vt2 : Vt;

    const f32x4 Z4 = {0.f, 0.f, 0.f, 0.f};
    f32x4 acc[4];
    for (int j = 0; j < 4; j++) acc[j] = Z4;

    const ushort* A16 = (const ushort*)Ain;
    const float*  A32 = (const float*)Ain;
    const int row = tid >> 2, off = (tid & 3) * 8;

    for (int k0 = 0; k0 < K; k0 += 32) {
        __syncthreads();
        if (a32) {
            const float* p0 = A32 + (size_t)(m0 + row) * K + k0 + off;
            float4 f0 = *(const float4*)p0;
            float4 f1 = *(const float4*)(p0 + 4);
            uint4 t0;
            t0.x = cvt_pk_bf16(f0.x, f0.y);
            t0.y = cvt_pk_bf16(f0.z, f0.w);
            t0.z = cvt_pk_bf16(f1.x, f1.y);
            t0.w = cvt_pk_bf16(f1.z, f1.w);
            *(uint4*)&As[row][off] = t0;
        } else {
            *(uint4*)&As[row][off] =
                *(const uint4*)(A16 + (size_t)(m0 + row) * K + k0 + off);
        }
        *(uint4*)&Ws[row][off] =
            *(const uint4*)(Wu + (size_t)(n0 + row) * K + k0 + off);
        __syncthreads();

        short8 af = *(const short8*)&As[w * 16 + lm][quad * 8];
        for (int nt = 0; nt < 4; nt++) {
            short8 wf = *(const short8*)&Ws[nt * 16 + lm][quad * 8];
            acc[nt] = MFMA16(af, wf, acc[nt]);
        }
    }

    const int grow = m0 + w * 16 + quad * 4;     // global C row (4 consecutive)
    const int grel = grow - (side ? mhalf : 0);  // row within half (Kh/Vt)
    if (mode == 1) {
        const float QSC = 0.17677669529663687f * 1.4426950408889634f;
        int bb = grel / 2304;
        int tok = grel - bb * 2304;              // 4-aligned; same bb for r=0..3
        for (int nt = 0; nt < 4; nt++) {
            int col = n0 + nt * 16 + lm;
            if (col < 256) {
                for (int r = 0; r < 4; r++)
                    C[(size_t)(grow + r) * 256 + col] = f2bf(acc[nt][r] * QSC);
            } else if (col < 512) {
                int c2 = col - 256, hh = c2 >> 5, d = c2 & 31;
                for (int r = 0; r < 4; r++)
                    Khu[(((size_t)bb * 8 + hh) * 2304 + tok + r) * 32 + d] = f2bf(acc[nt][r]);
            } else {
                int c2 = col - 512, hh = c2 >> 5, d = c2 & 31;
                uint2 o;
                o.x = cvt_pk_bf16(acc[nt][0], acc[nt][1]);
                o.y = cvt_pk_bf16(acc[nt][2], acc[nt][3]);
                *(uint2*)&Vtu[(((size_t)bb * 8 + hh) * 32 + d) * 2304 + tok] = o;
            }
        }
    } else {
        for (int nt = 0; nt < 4; nt++) {
            int col = n0 + nt * 16 + lm;
            float bv = bu ? bf2f(bu[col]) : 0.f;
            for (int r = 0; r < 4; r++) {
                float v = acc[nt][r] + bv;
                if (relu) v = fmaxf(v, 0.f);
                C[(size_t)(grow + r) * N + col] = f2bf(v);
            }
        }
    }
}

// ---------------------------------------------------------------------------
// Flash cross-attention, S^T form on 32x32x16 MFMA, no-max softmax
// (p = exp2(s), Q pre-scaled by scale*log2e in the QKV GEMM).
// Block = 2 waves x 32 q (64 q), 64-key chunks, grid (36, 64).
// Double-buffered K/V LDS; one raw barrier per chunk (lgkmcnt only);
// prefetch depth 2 with named A/B register sets. P^T redistribution fully
// in-register via cvt_pk + permlane32_swap. Split PV accumulators.
// Q:[B,2304,256]; Kh:[b][h][tok][32]; Vt:[b][h][d][2304]; O:[B,2304,256].
// ---------------------------------------------------------------------------
__global__ __launch_bounds__(128, 4) void attn_kernel(
    const ushort* __restrict__ Qa, const ushort* __restrict__ Kha,
    const ushort* __restrict__ Vta, ushort* __restrict__ Oa,
    const ushort* __restrict__ Qb, const ushort* __restrict__ Khb2,
    const ushort* __restrict__ Vtb2, ushort* __restrict__ Ob)
{
    __shared__ __align__(16) ushort Ksh[2][64][40];   // [buf][key][d]
    __shared__ __align__(16) ushort Vsh[2][32][72];   // [buf][d][tok]

    const int qb = blockIdx.x;            // 36 q-blocks of 64
    const int side = blockIdx.y >> 5;
    const int bh = blockIdx.y & 31;
    const ushort* Q  = side ? Qb   : Qa;
    const ushort* Kh = side ? Khb2 : Kha;
    const ushort* Vt = side ? Vtb2 : Vta;
    ushort* O        = side ? Ob   : Oa;

    const int b = bh >> 3, h = bh & 7;
    const int tid = threadIdx.x;
    const int w = tid >> 6, lane = tid & 63;
    const int l31 = lane & 31, hl = lane >> 5;

    // Q B-frags: lane holds q-col = l31, d = 16*dstep + hl*8 + j (persistent)
    const int qrow = qb * 64 + w * 32 + l31;
    const ushort* qp = Q + ((size_t)b * 2304 + qrow) * 256 + h * 32 + hl * 8;
    const short8 qf0 = *(const short8*)qp;          // d = hl*8 + j
    const short8 qf1 = *(const short8*)(qp + 16);   // d = 16 + hl*8 + j

    f32x16 o0, o1;
    #pragma unroll
    for (int i = 0; i < 16; i++) { o0[i] = 0.f; o1[i] = 0.f; }
    const f32x16 Z16 = o0;
    float l = 0.f;

    const ushort* Khb = Kh + (size_t)bh * 2304 * 32;
    const ushort* Vtb = Vt + (size_t)bh * 32 * 2304;
    const int k_r0 = tid >> 2, k_off = (tid & 3) * 8;   // K: rows r0, r0+32
    const int v_r0 = tid >> 3, v_off = (tid & 7) * 8;   // V: rows r0, r0+16

#define LOADK(d0, d1, cc) { \
    const ushort* _kp = Khb + ((size_t)((cc) * 64 + k_r0) * 32) + k_off; \
    d0 = *(const uint4*)_kp; \
    d1 = *(const uint4*)(_kp + 32 * 32); \
}
#define LOADV(d0, d1, cc) { \
    const ushort* _vp = Vtb + (size_t)v_r0 * 2304 + (cc) * 64 + v_off; \
    d0 = *(const uint4*)_vp; \
    d1 = *(const uint4*)(_vp + 16 * 2304); \
}
#define STORE(bi, ka, kb, va, vb) { \
    *(uint4*)&Ksh[bi][k_r0][k_off]      = ka; \
    *(uint4*)&Ksh[bi][k_r0 + 32][k_off] = kb; \
    *(uint4*)&Vsh[bi][v_r0][v_off]      = va; \
    *(uint4*)&Vsh[bi][v_r0 + 16][v_off] = vb; \
}
    // One 32-key tile: S^T MFMA pair -> exp2 -> pack/swap -> PV MFMA pair.
#define TILE(bi, t, oacc) { \
    short8 kf0 = *(const short8*)&Ksh[bi][(t) * 32 + l31][hl * 8]; \
    short8 kf1 = *(const short8*)&Ksh[bi][(t) * 32 + l31][16 + hl * 8]; \
    f32x16 s = MFMA32(kf0, qf0, Z16); \
    s = MFMA32(kf1, qf1, s); \
    float p[16]; \
    _Pragma("unroll") \
    for (int i = 0; i < 16; i++) p[i] = exp2f(s[i]); \
    l += (((p[0] + p[1]) + (p[2] + p[3])) + ((p[4] + p[5]) + (p[6] + p[7]))) \
       + (((p[8] + p[9]) + (p[10] + p[11])) + ((p[12] + p[13]) + (p[14] + p[15]))); \
    unsigned c0 = cvt_pk_bf16(p[0],  p[1]); \
    unsigned c1 = cvt_pk_bf16(p[2],  p[3]); \
    unsigned c2 = cvt_pk_bf16(p[4],  p[5]); \
    unsigned c3 = cvt_pk_bf16(p[6],  p[7]); \
    unsigned c4 = cvt_pk_bf16(p[8],  p[9]); \
    unsigned c5 = cvt_pk_bf16(p[10], p[11]); \
    unsigned c6 = cvt_pk_bf16(p[12], p[13]); \
    unsigned c7 = cvt_pk_bf16(p[14], p[15]); \
    plswap(c0, c2); plswap(c1, c3); plswap(c4, c6); plswap(c5, c7); \
    union { unsigned u[4]; short8 s8; } pA, pB; \
    pA.u[0] = c0; pA.u[1] = c1; pA.u[2] = c2; pA.u[3] = c3; \
    pB.u[0] = c4; pB.u[1] = c5; pB.u[2] = c6; pB.u[3] = c7; \
    short8 vf0 = *(const short8*)&Vsh[bi][l31][(t) * 32 + hl * 8]; \
    short8 vf1 = *(const short8*)&Vsh[bi][l31][(t) * 32 + 16 + hl * 8]; \
    oacc = MFMA32(vf0, pA.s8, oacc); \
    oacc = MFMA32(vf1, pB.s8, oacc); \
}

    uint4 kA0, kA1, vA0, vA1;    // set A: even chunks
    uint4 kB0, kB1, vB0, vB1;    // set B: odd chunks

    // Prologue: buf0 <- chunk0; B holds chunk1; A reloaded with chunk2.
    LOADK(kA0, kA1, 0); LOADV(vA0, vA1, 0);
    LOADK(kB0, kB1, 1); LOADV(vB0, vB1, 1);
    STORE(0, kA0, kA1, vA0, vA1);
    LOADK(kA0, kA1, 2); LOADV(vA0, vA1, 2);
    wavebar();

    for (int i = 0; i < 18; i++) {
        // even chunk 2i from buf0
        TILE(0, 0, o0); TILE(0, 1, o1);
        STORE(1, kB0, kB1, vB0, vB1);             // chunk 2i+1
        int c3 = 2 * i + 3; c3 = c3 < 36 ? c3 : 35;
        LOADK(kB0, kB1, c3); LOADV(vB0, vB1, c3);
        wavebar();
        // odd chunk 2i+1 from buf1
        TILE(1, 0, o0); TILE(1, 1, o1);
        STORE(0, kA0, kA1, vA0, vA1);             // chunk 2i+2 (clamped tail)
        int c4 = 2 * i + 4; c4 = c4 < 36 ? c4 : 35;
        LOADK(kA0, kA1, c4); LOADV(vA0, vA1, c4);
        wavebar();
    }
#undef LOADK
#undef LOADV
#undef STORE
#undef TILE

    // Lane halves hold disjoint key subsets for the same q: reduce l.
    l += __shfl_xor(l, 32, 64);
    float rl = 1.f / l;
    // o reg r: d = (r&3) + 8*(r>>2) + 4*hl, q = l31.
    ushort* op = O + ((size_t)b * 2304 + qrow) * 256 + h * 32 + hl * 4;
    #pragma unroll
    for (int g = 0; g < 4; g++) {
        float e0 = (o0[4 * g]     + o1[4 * g])     * rl;
        float e1 = (o0[4 * g + 1] + o1[4 * g + 1]) * rl;
        float e2 = (o0[4 * g + 2] + o1[4 * g + 2]) * rl;
        float e3 = (o0[4 * g + 3] + o1[4 * g + 3]) * rl;
        uint2 o;
        o.x = cvt_pk_bf16(e0, e1);
        o.y = cvt_pk_bf16(e2, e3);
        *(uint2*)(op + 8 * g) = o;
    }
}

// ---------------------------------------------------------------------------
// LayerNorm over C=256 fused with transpose to channel-major:
//   Z[18432][256] -> Yt[(half*4+b)*256 + c][2304]  (spatial innermost)
// ---------------------------------------------------------------------------
__global__ __launch_bounds__(256) void lnt_kernel(
    const ushort* __restrict__ Z, const ushort* __restrict__ G1,
    const ushort* __restrict__ B1, const ushort* __restrict__ G2,
    const ushort* __restrict__ B2, ushort* __restrict__ Yt)
{
    __shared__ ushort T[256][72];   // 36 KB

    const int tid = threadIdx.x;
    const int tok0 = blockIdx.x * 32;
    const int half = (tok0 >= 9216) ? 1 : 0;
    const int tr = tok0 - half * 9216;
    const int bb = tr / 2304;
    const int tokb = tr - bb * 2304;

    const int tok_l = tid >> 3;      // 0..31
    const int cq = tid & 7;          // c-chunk of 32

    const ushort* zp = Z + ((size_t)(tok0 + tok_l)) * 256 + cq * 32;
    uint dd[16];
    for (int i = 0; i < 4; i++) {
        uint4 v = *(const uint4*)(zp + i * 8);
        dd[i * 4 + 0] = v.x; dd[i * 4 + 1] = v.y;
        dd[i * 4 + 2] = v.z; dd[i * 4 + 3] = v.w;
    }
    float s = 0.f, q = 0.f;
    for (int e = 0; e < 16; e++) {
        float x0 = bf2f((ushort)dd[e]);
        float x1 = bf2f((ushort)(dd[e] >> 16));
        s += x0 + x1;
        q += x0 * x0 + x1 * x1;
    }
    s += __shfl_xor(s, 1, 64); q += __shfl_xor(q, 1, 64);
    s += __shfl_xor(s, 2, 64); q += __shfl_xor(q, 2, 64);
    s += __shfl_xor(s, 4, 64); q += __shfl_xor(q, 4, 64);
    float mu = s * (1.f / 256.f);
    float var = q * (1.f / 256.f) - mu * mu;
    float rs = rsqrtf(var + 1e-5f);

    const ushort* Gs = half ? G2 : G1;
    const ushort* Bs = half ? B2 : B1;
    const int col = tok_l + 4 * cq;          // rotation: c>>5 == cq here

    for (int i = 0; i < 4; i++) {
        int cb = cq * 32 + i * 8;
        uint4 gv = *(const uint4*)(Gs + cb);
        uint4 bv = *(const uint4*)(Bs + cb);
        uint gg[4] = {gv.x, gv.y, gv.z, gv.w};
        uint bw[4] = {bv.x, bv.y, bv.z, bv.w};
        for (int k = 0; k < 4; k++) {
            uint u = dd[i * 4 + k];
            float x0 = bf2f((ushort)u), x1 = bf2f((ushort)(u >> 16));
            float y0 = (x0 - mu) * rs * bf2f((ushort)gg[k]) + bf2f((ushort)bw[k]);
            float y1 = (x1 - mu) * rs * bf2f((ushort)(gg[k] >> 16))
                     + bf2f((ushort)(bw[k] >> 16));
            int c = cb + 2 * k;
            T[c][col]     = f2bf(y0);
            T[c + 1][col] = f2bf(y1);
        }
    }
    __syncthreads();

    // Pass 2: thread (c_row = tid>>3, tq = (tid&7)*4): 8 c rows, 4 toks each.
    const int c_row = tid >> 3;          // 0..31
    const int tq = (tid & 7) * 4;        // 0..28
    const size_t obase = ((size_t)((half * 4 + bb) * 256)) * 2304 + tokb + tq;
    for (int i = 0; i < 8; i++) {
        int c = c_row + 32 * i;          // c>>5 == i
        uint2 v = *(const uint2*)&T[c][tq + 4 * i];
        *(uint2*)(Yt + obase + (size_t)c * 2304) = v;
    }
}

// ---------------------------------------------------------------------------
// Bilinear 2x upsample from channel-major Yt[bc][48*48] (spatial contiguous).
// Each thread: one oj-pair -> float2 store.
// ---------------------------------------------------------------------------
__global__ __launch_bounds__(256) void upsample_kernel(
    const ushort* __restrict__ Yt, float* __restrict__ out)
{
    int idx = blockIdx.x * 256 + threadIdx.x;    // 36864 blocks
    int m  = idx % 48;
    int t  = idx / 48;
    int oi = t % 96;
    int bc = t / 96;                 // 0..2047

    float fi = oi * 0.5f - 0.25f;
    int i0 = (int)floorf(fi);
    float wi = fi - (float)i0;
    int i1 = i0 + 1 < 47 ? i0 + 1 : 47;
    i0 = i0 > 0 ? i0 : 0;
    int jm = m - 1 > 0 ? m - 1 : 0;
    int jp = m + 1 < 47 ? m + 1 : 47;

    const ushort* r0 = Yt + (size_t)bc * 2304 + i0 * 48;
    const ushort* r1 = Yt + (size_t)bc * 2304 + i1 * 48;
    float a0 = bf2f(r0[jm]), b0 = bf2f(r0[m]), c0 = bf2f(r0[jp]);
    float a1 = bf2f(r1[jm]), b1 = bf2f(r1[m]), c1 = bf2f(r1[jp]);
    float u = 1.f - wi;
    float ha = u * a0 + wi * a1;
    float hb = u * b0 + wi * b1;
    float hc = u * c0 + wi * c1;
    float2 o;
    o.x = 0.25f * ha + 0.75f * hb;
    o.y = 0.75f * hb + 0.25f * hc;
    *(float2*)(out + (size_t)bc * 9216 + oi * 96 + m * 2) = o;
}

// ---------------------------------------------------------------------------
extern "C" void kernel_launch(void* const* d_in, const int* in_sizes, int n_in,
                              void* d_out, int out_size, void* d_ws, size_t ws_size,
                              hipStream_t stream)
{
    (void)in_sizes; (void)n_in; (void)out_size; (void)ws_size;

    // ---- Buffer plan (stream-order-safe reuse; ~29.4 MB of ws) ----
    ushort* ws  = (ushort*)d_ws;
    ushort* Q1  = ws;                         // [9216,256]
    ushort* Q2  = Q1  + 2359296;              // contiguous with Q1
    ushort* KV1 = Q2  + 2359296;              // Kh1 + Vt1
    ushort* KV2 = KV1 + 4718592;              // Kh2 + Vt2
    ushort* wc  = KV2 + 4718592;              // canonical params
    int*    dflag = (int*)(wc + 525824);

    ushort* cqkv1w = wc;                      // [768,256] = q1w ++ kv1w
    ushort* cqkv2w = wc + 196608;             // [768,256] = q2w ++ kv2w
    ushort* cp1w  = wc + 393216;
    ushort* cp2w  = wc + 458752;
    ushort* cp1b  = wc + 524288;
    ushort* cp2b  = wc + 524544;
    ushort* cg1   = wc + 524800;
    ushort* cb1   = wc + 525056;
    ushort* cg2   = wc + 525312;
    ushort* cb2   = wc + 525568;

    float*  outf = (float*)d_out;
    ushort* O1  = (ushort*)d_out;             // bf16 staging (dead pre-upsample)
    ushort* O2  = O1 + 2359296;               // contiguous with O1
    ushort* Xb1 = O2 + 2359296;               // bf16 x1 (dead after QKV gemm)
    ushort* Xb2 = Xb1 + 2359296;              // contiguous with Xb1
    ushort* Z1  = KV2;                        // KV2 dead after attn (launch order)
    ushort* Yt  = Q1;                         // Q1+Q2 dead after attn: 9.4 MB
    (void)Q2; (void)O2; (void)Xb2;

    dim3 blk(256);
    sniff_kernel<<<dim3(1), dim3(64), 0, stream>>>((const ushort*)d_in[0], dflag);
    convert_params<<<dim3(2054), blk, 0, stream>>>(
        d_in[2], d_in[3], d_in[4], d_in[5], d_in[8], d_in[10],
        d_in[9], d_in[11], d_in[12], d_in[13], d_in[14], d_in[15],
        wc, dflag);
    convert_x<<<dim3(2304), blk, 0, stream>>>(d_in[0], d_in[1], Xb1, Xb2, dflag);

    // Merged Q+KV projections for BOTH inputs (M=18432, N=768):
    // Q scaled by scale*log2e, Kh per-head, Vt transposed.
    gemm_bt<<<dim3(288, 12), blk, 0, stream>>>(Xb1, cqkv1w, Q1, nullptr,
        18432, 768, 256, 0, dflag, 0, 1, KV1, KV1 + 2359296,
        cqkv2w, nullptr, KV2, KV2 + 2359296, 9216);

    // Both cross attentions in one dispatch (grid.y 0..31 = x1->x2 side,
    // 32..63 = x2->x1 side). 64 q per block, 2 waves.
    attn_kernel<<<dim3(36, 64), dim3(128), 0, stream>>>(
        Q1, KV2, KV2 + 2359296, O1,
        Q2, KV1, KV1 + 2359296, O2);

    // Merged output projection + bias + ReLU (M=18432).
    gemm_bt<<<dim3(288, 4), blk, 0, stream>>>(O1, cp1w, Z1, cp1b,
        18432, 256, 256, 1, dflag, 0, 0, nullptr, nullptr,
        cp2w, cp2b, nullptr, nullptr, 9216);

    // LayerNorm + transpose to channel-major (18432 tokens, 32/block).
    lnt_kernel<<<dim3(576), blk, 0, stream>>>(Z1, cg1, cb1, cg2, cb2, Yt);

    // Bilinear 2x upsample into d_out (float32, both outputs, float2/thread).
    upsample_kernel<<<dim3(36864), blk, 0, stream>>>(Yt, outf);
}

// Round 6
// 303.397 us; speedup vs baseline: 1.5393x; 1.5393x over previous
//
#include <hip/hip_runtime.h>
#include <math.h>

// ---------------------------------------------------------------------------
// CrossPath: dual cross-attention block, MI355X (gfx950).
//   B=4, N=2304, C=256, H=8, D=32, out = 2 x [B,C,96,96] float32
// Inputs float32 (runtime-sniffed). Internal: bf16 MFMA, fp32 accumulation.
// R13: R12's pipeline minus the spills. R12's __launch_bounds__(128,4) made
// the unified-VGPR allocator cap arch VGPRs at 64 -> ~45 regs spilled ->
// 1.1GB scratch traffic (WRITE_SIZE 638MB). Now: no min-waves bound, ONE
// prefetch register set (store chunk c to LDS, reload same regs with c+1).
// Keeps: double-buffered K/V LDS, one lgkmcnt-only barrier per chunk (no
// vmcnt drain at barriers), split o0/o1 accumulators, 2-wave blocks,
// grid 2304 = 9 blocks/CU.
// ---------------------------------------------------------------------------

typedef __attribute__((ext_vector_type(8))) short short8;   // 8 bf16 = 4 VGPRs
typedef __attribute__((ext_vector_type(4))) float f32x4;
typedef __attribute__((ext_vector_type(16))) float f32x16;
typedef __attribute__((ext_vector_type(2))) unsigned uint32x2;

#define MFMA16(a, b, c) __builtin_amdgcn_mfma_f32_16x16x32_bf16((a), (b), (c), 0, 0, 0)
#define MFMA32(a, b, c) __builtin_amdgcn_mfma_f32_32x32x16_bf16((a), (b), (c), 0, 0, 0)

__device__ __forceinline__ float bf2f(ushort u) {
    union { unsigned u; float f; } x; x.u = ((unsigned)u) << 16; return x.f;
}
__device__ __forceinline__ ushort f2bf(float f) {
    union { float f; unsigned u; } x; x.f = f;
    unsigned u = x.u;
    return (ushort)((u + 0x7fffu + ((u >> 16) & 1u)) >> 16);   // RNE
}
// HW packed RNE conversion: D = {bf16(b)<<16 | bf16(a)}
__device__ __forceinline__ unsigned cvt_pk_bf16(float a, float b) {
    unsigned r;
    asm("v_cvt_pk_bf16_f32 %0, %1, %2" : "=v"(r) : "v"(a), "v"(b));
    return r;
}
// Exchange upper 32 lanes of a with lower 32 lanes of b (gfx950 builtin).
__device__ __forceinline__ void plswap(unsigned &a, unsigned &b) {
    uint32x2 r = __builtin_amdgcn_permlane32_swap(a, b, false, false);
    a = r[0]; b = r[1];
}
// Workgroup barrier WITHOUT vmcnt drain: LDS ops complete, global loads
// (feeding only this wave's registers) stay in flight.
__device__ __forceinline__ void wavebar() {
    asm volatile("s_waitcnt lgkmcnt(0)" ::: "memory");
    __builtin_amdgcn_s_barrier();
}

// ---------------------------------------------------------------------------
// Dtype sniffer: flag=1 means f32 inputs.
// ---------------------------------------------------------------------------
__global__ void sniff_kernel(const ushort* __restrict__ x, int* __restrict__ flag)
{
    int lane = threadIdx.x;
    ushort u = x[lane * 2];
    int e = (u >> 7) & 0xFF;
    int outlier = (e < 100 || e > 135) ? 1 : 0;
    unsigned long long m = __ballot(outlier);
    if (lane == 0) *flag = (__popcll(m) >= 16) ? 1 : 0;
}

// ---------------------------------------------------------------------------
// Canonicalize all 12 weight/param arrays to bf16 at fixed offsets in ws.
// ---------------------------------------------------------------------------
__global__ __launch_bounds__(256) void convert_params(
    const void* s0, const void* s1, const void* s2, const void* s3,
    const void* s4, const void* s5, const void* s6, const void* s7,
    const void* s8, const void* s9, const void* s10, const void* s11,
    ushort* __restrict__ dst, const int* __restrict__ flag)
{
    int idx = blockIdx.x * 256 + threadIdx.x;
    if (idx >= 525824) return;
    const void* src; int off;
    if      (idx < 65536)  { src = s0;  off = idx; }
    else if (idx < 196608) { src = s1;  off = idx - 65536; }
    else if (idx < 262144) { src = s2;  off = idx - 196608; }
    else if (idx < 393216) { src = s3;  off = idx - 262144; }
    else if (idx < 458752) { src = s4;  off = idx - 393216; }
    else if (idx < 524288) { src = s5;  off = idx - 458752; }
    else if (idx < 524544) { src = s6;  off = idx - 524288; }
    else if (idx < 524800) { src = s7;  off = idx - 524544; }
    else if (idx < 525056) { src = s8;  off = idx - 524800; }
    else if (idx < 525312) { src = s9;  off = idx - 525056; }
    else if (idx < 525568) { src = s10; off = idx - 525312; }
    else                   { src = s11; off = idx - 525568; }
    ushort v = (*flag) ? f2bf(((const float*)src)[off])
                       : ((const ushort*)src)[off];
    dst[idx] = v;
}

// ---------------------------------------------------------------------------
// Pre-convert x1/x2 -> bf16 once (8 elems/thread).
// ---------------------------------------------------------------------------
__global__ __launch_bounds__(256) void convert_x(
    const void* __restrict__ x1, const void* __restrict__ x2,
    ushort* __restrict__ o1, ushort* __restrict__ o2,
    const int* __restrict__ flag)
{
    int idx = blockIdx.x * 256 + threadIdx.x;      // 2304 blocks -> 589824 thr
    int which = idx >= 294912;
    int off = (which ? idx - 294912 : idx) * 8;
    const void* src = which ? x2 : x1;
    ushort* dst = which ? o2 : o1;
    if (*flag) {
        const float* p = (const float*)src + off;
        float4 a = *(const float4*)p;
        float4 c = *(const float4*)(p + 4);
        uint4 u;
        u.x = cvt_pk_bf16(a.x, a.y);
        u.y = cvt_pk_bf16(a.z, a.w);
        u.z = cvt_pk_bf16(c.x, c.y);
        u.w = cvt_pk_bf16(c.z, c.w);
        *(uint4*)(dst + off) = u;
    } else {
        *(uint4*)(dst + off) = *(const uint4*)((const ushort*)src + off);
    }
}

// ---------------------------------------------------------------------------
// GEMM: C[M,N] = A[M,K]*W[N,K]^T, bf16 MFMA 16x16x32, tile 64x64, 4 waves.
// Two stacked problems (rows [0,mhalf) use W/bias/Kh/Vt, rows [mhalf,M) use
// W2/bias2/Kh2/Vt2). mode 0: plain C (+bias/relu). mode 1 (merged QKV,
// N=768): col<256 -> Q row-major SCALED by scale*log2e; col<512 ->
// Kh[b][h][tok][32]; else -> Vt[b][h][d][2304].
// ---------------------------------------------------------------------------
__global__ __launch_bounds__(256) void gemm_bt(
    const void* __restrict__ Ain, const ushort* __restrict__ W,
    ushort* __restrict__ C, const ushort* __restrict__ bias,
    int M, int N, int K, int relu, const int* __restrict__ dflag, int a_ext,
    int mode, ushort* __restrict__ Kh, ushort* __restrict__ Vt,
    const ushort* __restrict__ W2, const ushort* __restrict__ bias2,
    ushort* __restrict__ Kh2, ushort* __restrict__ Vt2, int mhalf)
{
    __shared__ __align__(16) ushort As[64][40];
    __shared__ __align__(16) ushort Ws[64][40];

    const int m0 = blockIdx.x * 64;
    const int n0 = blockIdx.y * 64;
    const int tid = threadIdx.x;
    const int w = tid >> 6;
    const int lane = tid & 63;
    const int lm = lane & 15;
    const int quad = lane >> 4;
    const int a32 = a_ext ? *dflag : 0;

    const int side = (mhalf && m0 >= mhalf) ? 1 : 0;
    const ushort* Wu = side ? W2 : W;
    const ushort* bu = side ? bias2 : bias;
    ushort* Khu = side ? Kh2 : Kh;
    ushort* Vtu = side ? Vt2 : Vt;

    const f32x4 Z4 = {0.f, 0.f, 0.f, 0.f};
    f32x4 acc[4];
    for (int j = 0; j < 4; j++) acc[j] = Z4;

    const ushort* A16 = (const ushort*)Ain;
    const float*  A32 = (const float*)Ain;
    const int row = tid >> 2, off = (tid & 3) * 8;

    for (int k0 = 0; k0 < K; k0 += 32) {
        __syncthreads();
        if (a32) {
            const float* p0 = A32 + (size_t)(m0 + row) * K + k0 + off;
            float4 f0 = *(const float4*)p0;
            float4 f1 = *(const float4*)(p0 + 4);
            uint4 t0;
            t0.x = cvt_pk_bf16(f0.x, f0.y);
            t0.y = cvt_pk_bf16(f0.z, f0.w);
            t0.z = cvt_pk_bf16(f1.x, f1.y);
            t0.w = cvt_pk_bf16(f1.z, f1.w);
            *(uint4*)&As[row][off] = t0;
        } else {
            *(uint4*)&As[row][off] =
                *(const uint4*)(A16 + (size_t)(m0 + row) * K + k0 + off);
        }
        *(uint4*)&Ws[row][off] =
            *(const uint4*)(Wu + (size_t)(n0 + row) * K + k0 + off);
        __syncthreads();

        short8 af = *(const short8*)&As[w * 16 + lm][quad * 8];
        for (int nt = 0; nt < 4; nt++) {
            short8 wf = *(const short8*)&Ws[nt * 16 + lm][quad * 8];
            acc[nt] = MFMA16(af, wf, acc[nt]);
        }
    }

    const int grow = m0 + w * 16 + quad * 4;     // global C row (4 consecutive)
    const int grel = grow - (side ? mhalf : 0);  // row within half (Kh/Vt)
    if (mode == 1) {
        const float QSC = 0.17677669529663687f * 1.4426950408889634f;
        int bb = grel / 2304;
        int tok = grel - bb * 2304;              // 4-aligned; same bb for r=0..3
        for (int nt = 0; nt < 4; nt++) {
            int col = n0 + nt * 16 + lm;
            if (col < 256) {
                for (int r = 0; r < 4; r++)
                    C[(size_t)(grow + r) * 256 + col] = f2bf(acc[nt][r] * QSC);
            } else if (col < 512) {
                int c2 = col - 256, hh = c2 >> 5, d = c2 & 31;
                for (int r = 0; r < 4; r++)
                    Khu[(((size_t)bb * 8 + hh) * 2304 + tok + r) * 32 + d] = f2bf(acc[nt][r]);
            } else {
                int c2 = col - 512, hh = c2 >> 5, d = c2 & 31;
                uint2 o;
                o.x = cvt_pk_bf16(acc[nt][0], acc[nt][1]);
                o.y = cvt_pk_bf16(acc[nt][2], acc[nt][3]);
                *(uint2*)&Vtu[(((size_t)bb * 8 + hh) * 32 + d) * 2304 + tok] = o;
            }
        }
    } else {
        for (int nt = 0; nt < 4; nt++) {
            int col = n0 + nt * 16 + lm;
            float bv = bu ? bf2f(bu[col]) : 0.f;
            for (int r = 0; r < 4; r++) {
                float v = acc[nt][r] + bv;
                if (relu) v = fmaxf(v, 0.f);
                C[(size_t)(grow + r) * N + col] = f2bf(v);
            }
        }
    }
}

// ---------------------------------------------------------------------------
// Flash cross-attention, S^T form on 32x32x16 MFMA, no-max softmax
// (p = exp2(s), Q pre-scaled by scale*log2e in the QKV GEMM).
// Block = 2 waves x 32 q (64 q), 64-key chunks, grid (36, 64).
// Double-buffered K/V LDS; one raw barrier per chunk (lgkmcnt only, no
// vmcnt drain); SINGLE prefetch register set (store chunk c -> LDS, then
// reload same regs with chunk c+1). P^T redistribution in-register via
// cvt_pk + permlane32_swap. Split PV accumulators o0/o1.
// Q:[B,2304,256]; Kh:[b][h][tok][32]; Vt:[b][h][d][2304]; O:[B,2304,256].
// ---------------------------------------------------------------------------
__global__ __launch_bounds__(128) void attn_kernel(
    const ushort* __restrict__ Qa, const ushort* __restrict__ Kha,
    const ushort* __restrict__ Vta, ushort* __restrict__ Oa,
    const ushort* __restrict__ Qb, const ushort* __restrict__ Khb2,
    const ushort* __restrict__ Vtb2, ushort* __restrict__ Ob)
{
    __shared__ __align__(16) ushort Ksh[2][64][40];   // [buf][key][d]
    __shared__ __align__(16) ushort Vsh[2][32][72];   // [buf][d][tok]

    const int qb = blockIdx.x;            // 36 q-blocks of 64
    const int side = blockIdx.y >> 5;
    const int bh = blockIdx.y & 31;
    const ushort* Q  = side ? Qb   : Qa;
    const ushort* Kh = side ? Khb2 : Kha;
    const ushort* Vt = side ? Vtb2 : Vta;
    ushort* O        = side ? Ob   : Oa;

    const int b = bh >> 3, h = bh & 7;
    const int tid = threadIdx.x;
    const int w = tid >> 6, lane = tid & 63;
    const int l31 = lane & 31, hl = lane >> 5;

    // Q B-frags: lane holds q-col = l31, d = 16*dstep + hl*8 + j (persistent)
    const int qrow = qb * 64 + w * 32 + l31;
    const ushort* qp = Q + ((size_t)b * 2304 + qrow) * 256 + h * 32 + hl * 8;
    const short8 qf0 = *(const short8*)qp;          // d = hl*8 + j
    const short8 qf1 = *(const short8*)(qp + 16);   // d = 16 + hl*8 + j

    f32x16 o0, o1;
    #pragma unroll
    for (int i = 0; i < 16; i++) { o0[i] = 0.f; o1[i] = 0.f; }
    const f32x16 Z16 = o0;
    float l = 0.f;

    const ushort* Khb = Kh + (size_t)bh * 2304 * 32;
    const ushort* Vtb = Vt + (size_t)bh * 32 * 2304;
    const int k_r0 = tid >> 2, k_off = (tid & 3) * 8;   // K: rows r0, r0+32
    const int v_r0 = tid >> 3, v_off = (tid & 7) * 8;   // V: rows r0, r0+16
    const ushort* kbase = Khb + (size_t)k_r0 * 32 + k_off;
    const ushort* vbase = Vtb + (size_t)v_r0 * 2304 + v_off;

#define LOADKV(cc) { \
    k0 = *(const uint4*)(kbase + (size_t)(cc) * 2048); \
    k1 = *(const uint4*)(kbase + (size_t)(cc) * 2048 + 32 * 32); \
    v0 = *(const uint4*)(vbase + (cc) * 64); \
    v1 = *(const uint4*)(vbase + (cc) * 64 + 16 * 2304); \
}
#define STORE(bi) { \
    *(uint4*)&Ksh[bi][k_r0][k_off]      = k0; \
    *(uint4*)&Ksh[bi][k_r0 + 32][k_off] = k1; \
    *(uint4*)&Vsh[bi][v_r0][v_off]      = v0; \
    *(uint4*)&Vsh[bi][v_r0 + 16][v_off] = v1; \
}
    // One 32-key tile: S^T MFMA pair -> exp2 -> pack/swap -> PV MFMA pair.
#define TILE(bi, t, oacc) { \
    short8 kf0 = *(const short8*)&Ksh[bi][(t) * 32 + l31][hl * 8]; \
    short8 kf1 = *(const short8*)&Ksh[bi][(t) * 32 + l31][16 + hl * 8]; \
    f32x16 s = MFMA32(kf0, qf0, Z16); \
    s = MFMA32(kf1, qf1, s); \
    float p[16]; \
    _Pragma("unroll") \
    for (int i = 0; i < 16; i++) p[i] = exp2f(s[i]); \
    l += (((p[0] + p[1]) + (p[2] + p[3])) + ((p[4] + p[5]) + (p[6] + p[7]))) \
       + (((p[8] + p[9]) + (p[10] + p[11])) + ((p[12] + p[13]) + (p[14] + p[15]))); \
    unsigned c0 = cvt_pk_bf16(p[0],  p[1]); \
    unsigned c1 = cvt_pk_bf16(p[2],  p[3]); \
    unsigned c2 = cvt_pk_bf16(p[4],  p[5]); \
    unsigned c3 = cvt_pk_bf16(p[6],  p[7]); \
    unsigned c4 = cvt_pk_bf16(p[8],  p[9]); \
    unsigned c5 = cvt_pk_bf16(p[10], p[11]); \
    unsigned c6 = cvt_pk_bf16(p[12], p[13]); \
    unsigned c7 = cvt_pk_bf16(p[14], p[15]); \
    plswap(c0, c2); plswap(c1, c3); plswap(c4, c6); plswap(c5, c7); \
    union { unsigned u[4]; short8 s8; } pA, pB; \
    pA.u[0] = c0; pA.u[1] = c1; pA.u[2] = c2; pA.u[3] = c3; \
    pB.u[0] = c4; pB.u[1] = c5; pB.u[2] = c6; pB.u[3] = c7; \
    short8 vf0 = *(const short8*)&Vsh[bi][l31][(t) * 32 + hl * 8]; \
    short8 vf1 = *(const short8*)&Vsh[bi][l31][(t) * 32 + 16 + hl * 8]; \
    oacc = MFMA32(vf0, pA.s8, oacc); \
    oacc = MFMA32(vf1, pB.s8, oacc); \
}

    uint4 k0, k1, v0, v1;    // single prefetch set

    // Prologue: buf0 <- chunk0; regs <- chunk1.
    LOADKV(0);
    STORE(0);
    LOADKV(1);
    wavebar();

    for (int i = 0; i < 17; i++) {            // chunks 2i, 2i+1
        TILE(0, 0, o0); TILE(0, 1, o1);       // chunk 2i from buf0
        STORE(1);                             // chunk 2i+1 -> buf1
        LOADKV(2 * i + 2);
        wavebar();
        TILE(1, 0, o0); TILE(1, 1, o1);       // chunk 2i+1 from buf1
        STORE(0);                             // chunk 2i+2 -> buf0
        int nc = 2 * i + 3; nc = nc < 36 ? nc : 35;
        LOADKV(nc);
        wavebar();
    }
    // Epilogue: buf0 = chunk 34, regs = chunk 35.
    TILE(0, 0, o0); TILE(0, 1, o1);
    STORE(1);
    wavebar();
    TILE(1, 0, o0); TILE(1, 1, o1);
#undef LOADKV
#undef STORE
#undef TILE

    // Lane halves hold disjoint key subsets for the same q: reduce l.
    l += __shfl_xor(l, 32, 64);
    float rl = 1.f / l;
    // o reg r: d = (r&3) + 8*(r>>2) + 4*hl, q = l31.
    ushort* op = O + ((size_t)b * 2304 + qrow) * 256 + h * 32 + hl * 4;
    #pragma unroll
    for (int g = 0; g < 4; g++) {
        float e0 = (o0[4 * g]     + o1[4 * g])     * rl;
        float e1 = (o0[4 * g + 1] + o1[4 * g + 1]) * rl;
        float e2 = (o0[4 * g + 2] + o1[4 * g + 2]) * rl;
        float e3 = (o0[4 * g + 3] + o1[4 * g + 3]) * rl;
        uint2 o;
        o.x = cvt_pk_bf16(e0, e1);
        o.y = cvt_pk_bf16(e2, e3);
        *(uint2*)(op + 8 * g) = o;
    }
}

// ---------------------------------------------------------------------------
// LayerNorm over C=256 fused with transpose to channel-major:
//   Z[18432][256] -> Yt[(half*4+b)*256 + c][2304]  (spatial innermost)
// ---------------------------------------------------------------------------
__global__ __launch_bounds__(256) void lnt_kernel(
    const ushort* __restrict__ Z, const ushort* __restrict__ G1,
    const ushort* __restrict__ B1, const ushort* __restrict__ G2,
    const ushort* __restrict__ B2, ushort* __restrict__ Yt)
{
    __shared__ ushort T[256][72];   // 36 KB

    const int tid = threadIdx.x;
    const int tok0 = blockIdx.x * 32;
    const int half = (tok0 >= 9216) ? 1 : 0;
    const int tr = tok0 - half * 9216;
    const int bb = tr / 2304;
    const int tokb = tr - bb * 2304;

    const int tok_l = tid >> 3;      // 0..31
    const int cq = tid & 7;          // c-chunk of 32

    const ushort* zp = Z + ((size_t)(tok0 + tok_l)) * 256 + cq * 32;
    uint dd[16];
    for (int i = 0; i < 4; i++) {
        uint4 v = *(const uint4*)(zp + i * 8);
        dd[i * 4 + 0] = v.x; dd[i * 4 + 1] = v.y;
        dd[i * 4 + 2] = v.z; dd[i * 4 + 3] = v.w;
    }
    float s = 0.f, q = 0.f;
    for (int e = 0; e < 16; e++) {
        float x0 = bf2f((ushort)dd[e]);
        float x1 = bf2f((ushort)(dd[e] >> 16));
        s += x0 + x1;
        q += x0 * x0 + x1 * x1;
    }
    s += __shfl_xor(s, 1, 64); q += __shfl_xor(q, 1, 64);
    s += __shfl_xor(s, 2, 64); q += __shfl_xor(q, 2, 64);
    s += __shfl_xor(s, 4, 64); q += __shfl_xor(q, 4, 64);
    float mu = s * (1.f / 256.f);
    float var = q * (1.f / 256.f) - mu * mu;
    float rs = rsqrtf(var + 1e-5f);

    const ushort* Gs = half ? G2 : G1;
    const ushort* Bs = half ? B2 : B1;
    const int col = tok_l + 4 * cq;          // rotation: c>>5 == cq here

    for (int i = 0; i < 4; i++) {
        int cb = cq * 32 + i * 8;
        uint4 gv = *(const uint4*)(Gs + cb);
        uint4 bv = *(const uint4*)(Bs + cb);
        uint gg[4] = {gv.x, gv.y, gv.z, gv.w};
        uint bw[4] = {bv.x, bv.y, bv.z, bv.w};
        for (int k = 0; k < 4; k++) {
            uint u = dd[i * 4 + k];
            float x0 = bf2f((ushort)u), x1 = bf2f((ushort)(u >> 16));
            float y0 = (x0 - mu) * rs * bf2f((ushort)gg[k]) + bf2f((ushort)bw[k]);
            float y1 = (x1 - mu) * rs * bf2f((ushort)(gg[k] >> 16))
                     + bf2f((ushort)(bw[k] >> 16));
            int c = cb + 2 * k;
            T[c][col]     = f2bf(y0);
            T[c + 1][col] = f2bf(y1);
        }
    }
    __syncthreads();

    // Pass 2: thread (c_row = tid>>3, tq = (tid&7)*4): 8 c rows, 4 toks each.
    const int c_row = tid >> 3;          // 0..31
    const int tq = (tid & 7) * 4;        // 0..28
    const size_t obase = ((size_t)((half * 4 + bb) * 256)) * 2304 + tokb + tq;
    for (int i = 0; i < 8; i++) {
        int c = c_row + 32 * i;          // c>>5 == i
        uint2 v = *(const uint2*)&T[c][tq + 4 * i];
        *(uint2*)(Yt + obase + (size_t)c * 2304) = v;
    }
}

// ---------------------------------------------------------------------------
// Bilinear 2x upsample from channel-major Yt[bc][48*48] (spatial contiguous).
// Each thread: one oj-pair -> float2 store.
// ---------------------------------------------------------------------------
__global__ __launch_bounds__(256) void upsample_kernel(
    const ushort* __restrict__ Yt, float* __restrict__ out)
{
    int idx = blockIdx.x * 256 + threadIdx.x;    // 36864 blocks
    int m  = idx % 48;
    int t  = idx / 48;
    int oi = t % 96;
    int bc = t / 96;                 // 0..2047

    float fi = oi * 0.5f - 0.25f;
    int i0 = (int)floorf(fi);
    float wi = fi - (float)i0;
    int i1 = i0 + 1 < 47 ? i0 + 1 : 47;
    i0 = i0 > 0 ? i0 : 0;
    int jm = m - 1 > 0 ? m - 1 : 0;
    int jp = m + 1 < 47 ? m + 1 : 47;

    const ushort* r0 = Yt + (size_t)bc * 2304 + i0 * 48;
    const ushort* r1 = Yt + (size_t)bc * 2304 + i1 * 48;
    float a0 = bf2f(r0[jm]), b0 = bf2f(r0[m]), c0 = bf2f(r0[jp]);
    float a1 = bf2f(r1[jm]), b1 = bf2f(r1[m]), c1 = bf2f(r1[jp]);
    float u = 1.f - wi;
    float ha = u * a0 + wi * a1;
    float hb = u * b0 + wi * b1;
    float hc = u * c0 + wi * c1;
    float2 o;
    o.x = 0.25f * ha + 0.75f * hb;
    o.y = 0.75f * hb + 0.25f * hc;
    *(float2*)(out + (size_t)bc * 9216 + oi * 96 + m * 2) = o;
}

// ---------------------------------------------------------------------------
extern "C" void kernel_launch(void* const* d_in, const int* in_sizes, int n_in,
                              void* d_out, int out_size, void* d_ws, size_t ws_size,
                              hipStream_t stream)
{
    (void)in_sizes; (void)n_in; (void)out_size; (void)ws_size;

    // ---- Buffer plan (stream-order-safe reuse; ~29.4 MB of ws) ----
    ushort* ws  = (ushort*)d_ws;
    ushort* Q1  = ws;                         // [9216,256]
    ushort* Q2  = Q1  + 2359296;              // contiguous with Q1
    ushort* KV1 = Q2  + 2359296;              // Kh1 + Vt1
    ushort* KV2 = KV1 + 4718592;              // Kh2 + Vt2
    ushort* wc  = KV2 + 4718592;              // canonical params
    int*    dflag = (int*)(wc + 525824);

    ushort* cqkv1w = wc;                      // [768,256] = q1w ++ kv1w
    ushort* cqkv2w = wc + 196608;             // [768,256] = q2w ++ kv2w
    ushort* cp1w  = wc + 393216;
    ushort* cp2w  = wc + 458752;
    ushort* cp1b  = wc + 524288;
    ushort* cp2b  = wc + 524544;
    ushort* cg1   = wc + 524800;
    ushort* cb1   = wc + 525056;
    ushort* cg2   = wc + 525312;
    ushort* cb2   = wc + 525568;

    float*  outf = (float*)d_out;
    ushort* O1  = (ushort*)d_out;             // bf16 staging (dead pre-upsample)
    ushort* O2  = O1 + 2359296;               // contiguous with O1
    ushort* Xb1 = O2 + 2359296;               // bf16 x1 (dead after QKV gemm)
    ushort* Xb2 = Xb1 + 2359296;              // contiguous with Xb1
    ushort* Z1  = KV2;                        // KV2 dead after attn (launch order)
    ushort* Yt  = Q1;                         // Q1+Q2 dead after attn: 9.4 MB
    (void)Q2; (void)O2; (void)Xb2;

    dim3 blk(256);
    sniff_kernel<<<dim3(1), dim3(64), 0, stream>>>((const ushort*)d_in[0], dflag);
    convert_params<<<dim3(2054), blk, 0, stream>>>(
        d_in[2], d_in[3], d_in[4], d_in[5], d_in[8], d_in[10],
        d_in[9], d_in[11], d_in[12], d_in[13], d_in[14], d_in[15],
        wc, dflag);
    convert_x<<<dim3(2304), blk, 0, stream>>>(d_in[0], d_in[1], Xb1, Xb2, dflag);

    // Merged Q+KV projections for BOTH inputs (M=18432, N=768):
    // Q scaled by scale*log2e, Kh per-head, Vt transposed.
    gemm_bt<<<dim3(288, 12), blk, 0, stream>>>(Xb1, cqkv1w, Q1, nullptr,
        18432, 768, 256, 0, dflag, 0, 1, KV1, KV1 + 2359296,
        cqkv2w, nullptr, KV2, KV2 + 2359296, 9216);

    // Both cross attentions in one dispatch (grid.y 0..31 = x1->x2 side,
    // 32..63 = x2->x1 side). 64 q per block, 2 waves.
    attn_kernel<<<dim3(36, 64), dim3(128), 0, stream>>>(
        Q1, KV2, KV2 + 2359296, O1,
        Q2, KV1, KV1 + 2359296, O2);

    // Merged output projection + bias + ReLU (M=18432).
    gemm_bt<<<dim3(288, 4), blk, 0, stream>>>(O1, cp1w, Z1, cp1b,
        18432, 256, 256, 1, dflag, 0, 0, nullptr, nullptr,
        cp2w, cp2b, nullptr, nullptr, 9216);

    // LayerNorm + transpose to channel-major (18432 tokens, 32/block).
    lnt_kernel<<<dim3(576), blk, 0, stream>>>(Z1, cg1, cb1, cg2, cb2, Yt);

    // Bilinear 2x upsample into d_out (float32, both outputs, float2/thread).
    upsample_kernel<<<dim3(36864), blk, 0, stream>>>(Yt, outf);
}